// Round 8
// baseline (1044.837 us; speedup 1.0000x reference)
//
#include <hip/hip_runtime.h>
#include <stdint.h>

#define B_    128
#define F_    4
#define V_    2048
#define D_    4096
#define DW    64      // D/64 bit-words per (b,f) row
#define VW    32      // V/64 bit-words per d column
#define ITERS 20
#define NKT   16      // K tiles of 128 over V=2048
#define NBLK  1024

typedef _Float16 half8 __attribute__((ext_vector_type(8)));
typedef float   floatx4 __attribute__((ext_vector_type(4)));

// ---- device-coherent (cross-XCD) access helpers: relaxed agent atomics.
__device__ __forceinline__ uint64_t cload64(const uint64_t* p) {
    return __hip_atomic_load(p, __ATOMIC_RELAXED, __HIP_MEMORY_SCOPE_AGENT);
}
__device__ __forceinline__ void cstore64(uint64_t* p, uint64_t v) {
    __hip_atomic_store(p, v, __ATOMIC_RELAXED, __HIP_MEMORY_SCOPE_AGENT);
}
__device__ __forceinline__ ulonglong2 cload_u128(const uint64_t* p) {
    ulonglong2 r;
    r.x = cload64(p); r.y = cload64(p + 1);
    return r;
}
__device__ __forceinline__ half8 cload_h8(const _Float16* p) {
    union { uint64_t q[2]; half8 h; } u;
    u.q[0] = cload64((const uint64_t*)p);
    u.q[1] = cload64((const uint64_t*)p + 1);
    return u.h;
}

// ---- grid barrier: monotone striped ticket (NO fences, NO resets).
// 16 stripes x (NBLK/16) arrivals per generation -> 1 master counter.
// Bounded spins: co-residency failure => wrong answer, never a hang.
__device__ __forceinline__ void xbar(int* bar, int gen) {
    __syncthreads();
    if (threadIdx.x == 0) {
        int s = blockIdx.x & 15;
        int t = __hip_atomic_fetch_add(&bar[s * 16], 1, __ATOMIC_RELAXED,
                                       __HIP_MEMORY_SCOPE_AGENT);
        if (t == gen * (NBLK / 16) - 1)
            __hip_atomic_fetch_add(&bar[256], 1, __ATOMIC_RELAXED,
                                   __HIP_MEMORY_SCOPE_AGENT);
        int spins = 0;
        while (__hip_atomic_load(&bar[256], __ATOMIC_RELAXED,
                                 __HIP_MEMORY_SCOPE_AGENT) < gen * 16) {
            __builtin_amdgcn_s_sleep(2);
            if (++spins > (1 << 16)) break;
        }
    }
    __syncthreads();
}

__device__ __forceinline__ void pack16(const float* __restrict__ x,
                                       uint64_t* __restrict__ bits, int t) {
    const float4* p = (const float4*)x + (size_t)t * 4;
    uint32_t m = 0;
    #pragma unroll
    for (int j = 0; j < 4; ++j) {
        float4 v = p[j];
        m |= (__float_as_uint(v.x) >> 31) << (4 * j + 0);
        m |= (__float_as_uint(v.y) >> 31) << (4 * j + 1);
        m |= (__float_as_uint(v.z) >> 31) << (4 * j + 2);
        m |= (__float_as_uint(v.w) >> 31) << (4 * j + 3);
    }
    ((unsigned short*)bits)[t] = (unsigned short)m;
}

// ------------------------------------------------------------------
// Setup: all three bit-packs + flag/key zeroing (R6-verified).
// ------------------------------------------------------------------
__global__ __launch_bounds__(256) void k_setup(
        const float* __restrict__ cb, const float* __restrict__ inite,
        const float* __restrict__ inputs,
        uint64_t* __restrict__ cb_bits, uint64_t* __restrict__ est_bits,
        uint64_t* __restrict__ in_bits,
        int* __restrict__ flags, int* __restrict__ keys) {
    int gtid = blockIdx.x * 256 + threadIdx.x;
    const int T = 512 * 256;
    const int ncb = (F_ * V_ * D_) / 16;
    for (int t = gtid; t < ncb; t += T) pack16(cb, cb_bits, t);
    pack16(inite, est_bits, gtid);
    if (gtid < (B_ * D_) / 16) pack16(inputs, in_bits, gtid);
    if (gtid < 32) flags[gtid] = 0;
    if (gtid < B_ * F_) keys[gtid] = 0;
}

// ------------------------------------------------------------------
// Transpose cb_bits[f][v][dwords] -> cbT[f][d][vwords] (R6-verified).
// ------------------------------------------------------------------
__global__ void k_packT(const uint64_t* __restrict__ cb_bits,
                        uint64_t* __restrict__ cbT) {
    int vw = blockIdx.x, dwg = blockIdx.y, f = blockIdx.z;
    int lane = threadIdx.x & 63;
    int dw = dwg * 4 + (threadIdx.x >> 6);
    uint64_t w = cb_bits[((size_t)f * V_ + vw * 64 + lane) * DW + dw];
    uint64_t r = 0;
    for (int d2 = 0; d2 < 64; ++d2) {
        uint64_t m = __ballot((unsigned)((w >> d2) & 1));
        if (lane == d2) r = m;
    }
    cbT[((size_t)f * D_ + dw * 64 + lane) * VW + vw] = r;
}

// ------------------------------------------------------------------
// Persistent loop v2: 1024 blocks x 256 thr, 32 KB LDS,
// launch_bounds(256,4) => 4 blocks/CU = 16 waves/CU co-resident
// (R7 ran 2 blocks/CU = 8 waves/CU, VALUBusy 47% = latency-bound).
// Same verified algorithms, tiles halved:
//   sim:  32v x 32b  (was 64v x 32b), grid 64vt x 4bt x 4f
//   gemm: 32m x 64n  (was 64m x 64n), grid 64nt x 4mt x 4f
// ------------------------------------------------------------------
__global__ __launch_bounds__(256, 4) void k_loop(
        const uint64_t* __restrict__ cb_bits, const uint64_t* __restrict__ cbT,
        uint64_t* __restrict__ est_bits, const uint64_t* __restrict__ in_bits,
        _Float16* __restrict__ simf, int* __restrict__ flags, int* bar) {
    const int bid = blockIdx.x;
    const int tid = threadIdx.x;
    int g = 0;

    __shared__ __align__(16) unsigned char LDSU[32768];   // 32 KB, phase-reused
    __shared__ int bd;

    #pragma unroll 1
    for (int i = 0; i < ITERS; ++i) {
        // ---- sim: LDS bit-GEMM, tile 32v x 32b ----
        {
            int vt = bid & 63, bt = (bid >> 6) & 3, f = bid >> 8;
            int v0 = vt * 32, b0 = bt * 32;
            ulonglong2* CB2 = (ulonglong2*)LDSU;            // 32*32 chunks, 16 KB
            ulonglong2* NB2 = (ulonglong2*)(LDSU + 16384);  // 32*32 chunks, 16 KB
            #pragma unroll
            for (int it = 0; it < 4; ++it) {
                int cq = it * 256 + tid;                    // 1024 chunks
                int r = cq >> 5, ch = cq & 31;
                const ulonglong2* src = (const ulonglong2*)(cb_bits + ((size_t)f * V_ + v0 + r) * DW);
                CB2[r * 32 + (ch ^ (r & 7))] = src[ch];     // read-only: cached
            }
            #pragma unroll
            for (int it = 0; it < 4; ++it) {
                int cq = it * 256 + tid;                    // 1024 chunks
                int r = cq >> 5, ch = cq & 31;
                int b = b0 + r;
                const ulonglong2* iv = (const ulonglong2*)(in_bits + (size_t)b * DW);
                const uint64_t* eb = est_bits + (size_t)b * F_ * DW;
                ulonglong2 i2 = iv[ch];                     // read-only: cached
                ulonglong2 e0 = cload_u128(eb + 0 * DW + 2 * ch);
                ulonglong2 e1 = cload_u128(eb + 1 * DW + 2 * ch);
                ulonglong2 e2 = cload_u128(eb + 2 * DW + 2 * ch);
                ulonglong2 e3 = cload_u128(eb + 3 * DW + 2 * ch);
                uint64_t ex = (f == 0) ? e0.x : (f == 1) ? e1.x : (f == 2) ? e2.x : e3.x;
                uint64_t ey = (f == 0) ? e0.y : (f == 1) ? e1.y : (f == 2) ? e2.y : e3.y;
                ulonglong2 val;
                val.x = i2.x ^ e0.x ^ e1.x ^ e2.x ^ e3.x ^ ex;
                val.y = i2.y ^ e0.y ^ e1.y ^ e2.y ^ e3.y ^ ey;
                NB2[r * 32 + (ch ^ (r & 7))] = val;
            }
            __syncthreads();

            int vv = tid & 15, bb = tid >> 4;
            int svz = vv & 7, sbz = bb & 7;
            int pc[2][2];
            #pragma unroll
            for (int j = 0; j < 2; ++j)
                #pragma unroll
                for (int ii = 0; ii < 2; ++ii) pc[j][ii] = 0;

            #pragma unroll 4
            for (int ch = 0; ch < 32; ++ch) {
                ulonglong2 c[2], n[2];
                #pragma unroll
                for (int ii = 0; ii < 2; ++ii)
                    c[ii] = CB2[(vv + 16 * ii) * 32 + (ch ^ svz)];
                #pragma unroll
                for (int j = 0; j < 2; ++j)
                    n[j] = NB2[(bb + 16 * j) * 32 + (ch ^ sbz)];
                #pragma unroll
                for (int j = 0; j < 2; ++j)
                    #pragma unroll
                    for (int ii = 0; ii < 2; ++ii)
                        pc[j][ii] += __popcll(n[j].x ^ c[ii].x) + __popcll(n[j].y ^ c[ii].y);
            }
            // coherent simf store: pair adjacent lanes (v, v+1) into one u32
            #pragma unroll
            for (int j = 0; j < 2; ++j) {
                int b = b0 + bb + 16 * j;
                #pragma unroll
                for (int ii = 0; ii < 2; ++ii) {
                    int v = v0 + vv + 16 * ii;
                    union { _Float16 hf; unsigned short us; } cv;
                    cv.hf = (_Float16)(2048 - pc[j][ii]);
                    int other = __shfl_xor((int)cv.us, 1, 64);
                    if (!(vv & 1)) {
                        uint32_t packv = (uint32_t)cv.us | ((uint32_t)other << 16);
                        __hip_atomic_store(
                            (uint32_t*)&simf[((size_t)f * B_ + b) * V_ + v], packv,
                            __ATOMIC_RELAXED, __HIP_MEMORY_SCOPE_AGENT);
                    }
                }
            }
        }
        xbar(bar, ++g);

        // ---- gemm: C = sim x (+-1 from cbT); hardsign -> est_bits ----
        // tile 32m x 64n; 4 waves, wave tile 16m x 32n.
        {
            int gnt = bid & 63, gmt = (bid >> 6) & 3, gf = bid >> 8;
            int m0 = gmt * 32, n0 = gnt * 64;
            int lane = tid & 63, wave = tid >> 6;
            int lrow = lane & 15, lq = lane >> 4;
            int wm = wave & 1, wn = wave >> 1;

            uint64_t* Bb = (uint64_t*)LDSU;                 // 64d x 32vw, 16 KB
            _Float16* As = (_Float16*)(LDSU + 16384);       // 32 x 128, 8 KB
            if (tid == 0) bd = 0;

            const uint64_t* bsrc = cbT + ((size_t)gf * D_ + n0) * VW;
            #pragma unroll
            for (int p = 0; p < 4; ++p) {
                int chunk = p * 256 + tid;                  // 1024 chunks
                int dloc = chunk >> 4, cw = chunk & 15;
                ulonglong2 val = *(const ulonglong2*)&bsrc[dloc * VW + cw * 2];  // cached
                *(ulonglong2*)&Bb[dloc * VW + ((cw ^ (dloc & 15)) * 2)] = val;
            }

            const _Float16* Ab = simf + (size_t)gf * B_ * V_ + (size_t)m0 * V_;
            int arow = tid >> 4, acol = tid & 15;           // 16 rows x 16 chunks
            half8 areg[2];
            #pragma unroll
            for (int p = 0; p < 2; ++p)
                areg[p] = cload_h8(&Ab[(size_t)(p * 16 + arow) * V_ + acol * 8]);

            floatx4 acc[2] = {};

            const uint64_t SPREAD = 0x1000200040008000ull;  // bit b -> pos 15+16b
            const uint64_t SMASK  = 0x8000800080008000ull;
            const uint64_t PONE   = 0x3C003C003C003C00ull;  // f16 +1.0 x4

            #pragma unroll 1
            for (int kt = 0; kt < NKT; ++kt) {
                __syncthreads();
                #pragma unroll
                for (int p = 0; p < 2; ++p)
                    *(half8*)&As[(p * 16 + arow) * 128 + ((acol ^ arow) * 8)] = areg[p];
                if (kt + 1 < NKT) {
                    #pragma unroll
                    for (int p = 0; p < 2; ++p)
                        areg[p] = cload_h8(&Ab[(size_t)(p * 16 + arow) * V_ + (kt + 1) * 128 + acol * 8]);
                }
                __syncthreads();

                ulonglong2 bw[2];
                #pragma unroll
                for (int nt2 = 0; nt2 < 2; ++nt2) {
                    int dloc = wn * 32 + nt2 * 16 + lrow;
                    bw[nt2] = *(const ulonglong2*)&Bb[dloc * VW + ((kt ^ (dloc & 15)) * 2)];
                }
                #pragma unroll
                for (int ks = 0; ks < 4; ++ks) {
                    half8 af;
                    {
                        int row = wm * 16 + lrow;
                        af = *(const half8*)&As[row * 128 + (((ks * 4 + lq) ^ lrow) * 8)];
                    }
                    #pragma unroll
                    for (int nt2 = 0; nt2 < 2; ++nt2) {
                        uint64_t w = (ks < 2) ? bw[nt2].x : bw[nt2].y;
                        uint32_t byte = (uint32_t)(w >> ((((ks & 1) * 4 + lq)) * 8)) & 0xFFu;
                        union { uint64_t q[2]; half8 h; } bu;
                        bu.q[0] = (((uint64_t)(byte & 0xFu) * SPREAD) & SMASK) ^ PONE;
                        bu.q[1] = (((uint64_t)(byte >> 4)   * SPREAD) & SMASK) ^ PONE;
                        acc[nt2] = __builtin_amdgcn_mfma_f32_16x16x32_f16(
                            af, bu.h, acc[nt2], 0, 0, 0);
                    }
                }
            }

            // epilogue: hardsign -> LDS bytes -> bit-pack u64 per row
            __syncthreads();
            unsigned char* S = (unsigned char*)As;          // 32 x 64 bytes
            #pragma unroll
            for (int nt2 = 0; nt2 < 2; ++nt2)
                #pragma unroll
                for (int r = 0; r < 4; ++r) {
                    int row = wm * 16 + lq * 4 + r;         // C/D: row = quad*4+reg
                    int col = wn * 32 + nt2 * 16 + lrow;    // col = lane&15
                    S[row * 64 + col] = (acc[nt2][r] < 0.0f) ? 1 : 0;  // sign(0)=+1
                }
            __syncthreads();
            if (tid < 32) {
                const uint64_t* Sw = (const uint64_t*)S;
                uint64_t m = 0;
                #pragma unroll
                for (int j = 0; j < 8; ++j) {
                    uint64_t w = Sw[tid * 8 + j];           // 8 bytes of 0/1
                    m |= ((w * 0x0102040810204080ull) >> 56) << (8 * j);
                }
                size_t widx = ((size_t)(m0 + tid) * F_ + gf) * DW + gnt;
                uint64_t old = cload64(&est_bits[widx]);
                cstore64(&est_bits[widx], m);
                if (old != m) atomicOr(&bd, 1);
            }
            __syncthreads();
            if (tid == 0 && bd) atomicOr(&flags[i], 1);
        }
        if (i + 1 < ITERS) xbar(bar, ++g);
    }
}

// ------------------------------------------------------------------
// argmax (R6-verified). grid (vt=64, f=4), 80 KB LDS.
// ------------------------------------------------------------------
__global__ __launch_bounds__(256) void k_argmax(
        const uint64_t* __restrict__ cb_bits,
        const uint64_t* __restrict__ est_bits,
        int* __restrict__ keys) {
    int vt = blockIdx.x, f = blockIdx.y;
    int v0 = vt * 32;
    int tid = threadIdx.x;

    __shared__ __align__(16) ulonglong2 EB2[128 * 32];  // 64 KB
    __shared__ __align__(16) ulonglong2 CBa[32 * 32];   // 16 KB

    #pragma unroll
    for (int it = 0; it < 16; ++it) {
        int cq = it * 256 + tid;
        int r = cq >> 5, ch = cq & 31;
        const ulonglong2* src = (const ulonglong2*)(est_bits + ((size_t)r * F_ + f) * DW);
        EB2[r * 32 + (ch ^ (r & 7))] = src[ch];
    }
    #pragma unroll
    for (int it = 0; it < 4; ++it) {
        int cq = it * 256 + tid;
        int r = cq >> 5, ch = cq & 31;
        const ulonglong2* src = (const ulonglong2*)(cb_bits + ((size_t)f * V_ + v0 + r) * DW);
        CBa[r * 32 + (ch ^ (r & 7))] = src[ch];
    }
    __syncthreads();

    int vv = tid & 15, bb = tid >> 4;
    int svz = vv & 7, sbz = bb & 7;
    int pc[8][2];
    #pragma unroll
    for (int j = 0; j < 8; ++j) { pc[j][0] = 0; pc[j][1] = 0; }

    #pragma unroll 4
    for (int ch = 0; ch < 32; ++ch) {
        ulonglong2 c[2], n[8];
        #pragma unroll
        for (int i = 0; i < 2; ++i)
            c[i] = CBa[(vv + 16 * i) * 32 + (ch ^ svz)];
        #pragma unroll
        for (int j = 0; j < 8; ++j)
            n[j] = EB2[(bb + 16 * j) * 32 + (ch ^ sbz)];
        #pragma unroll
        for (int j = 0; j < 8; ++j)
            #pragma unroll
            for (int i = 0; i < 2; ++i)
                pc[j][i] += __popcll(n[j].x ^ c[i].x) + __popcll(n[j].y ^ c[i].y);
    }

    #pragma unroll
    for (int j = 0; j < 8; ++j) {
        int kj = (int)0x80000000;
        #pragma unroll
        for (int i = 0; i < 2; ++i) {
            int v = v0 + vv + 16 * i;
            int m = 2048 - pc[j][i]; if (m < 0) m = -m;
            int key = (m << 11) | (2047 - v);
            if (key > kj) kj = key;
        }
        #pragma unroll
        for (int s = 1; s < 16; s <<= 1) {
            int o = __shfl_xor(kj, s, 64);
            if (o > kj) kj = o;
        }
        if ((tid & 15) == 0)
            atomicMax(&keys[(size_t)(bb + 16 * j) * F_ + f], kj);
    }
}

__global__ void k_final(const int* __restrict__ keys, const int* __restrict__ flags,
                        int* __restrict__ out) {
    int tid = blockIdx.x * blockDim.x + threadIdx.x;
    if (tid < B_ * F_) out[tid] = 2047 - (keys[tid] & 0x7FF);
    if (tid == 0) {
        int k = ITERS - 1;
        for (int i = 0; i < ITERS; ++i) if (flags[i] == 0) { k = i; break; }
        out[B_ * F_] = k;
    }
}

// ------------------------------------------------------------------
extern "C" void kernel_launch(void* const* d_in, const int* in_sizes, int n_in,
                              void* d_out, int out_size, void* d_ws, size_t ws_size,
                              hipStream_t stream) {
    const float* inputs = (const float*)d_in[0];   // (B, D)
    const float* inite  = (const float*)d_in[1];   // (B, F, D)
    const float* cb     = (const float*)d_in[2];   // (F, V, D)
    int* out = (int*)d_out;                        // 512 outcome + 1 k

    char* ws = (char*)d_ws;
    uint64_t* cb_bits  = (uint64_t*)ws;  ws += (size_t)F_ * V_ * DW * 8;   // 4 MiB
    uint64_t* cbT_bits = (uint64_t*)ws;  ws += (size_t)F_ * D_ * VW * 8;   // 4 MiB
    uint64_t* est_bits = (uint64_t*)ws;  ws += (size_t)B_ * F_ * DW * 8;   // 256 KiB
    uint64_t* in_bits  = (uint64_t*)ws;  ws += (size_t)B_ * DW * 8;        // 64 KiB
    _Float16* simf     = (_Float16*)ws;  ws += (size_t)F_ * B_ * V_ * 2;   // 2 MiB
    int*      flags    = (int*)ws;       ws += 32 * 4;
    int*      keys     = (int*)ws;       ws += B_ * F_ * 4;
    int*      bar      = (int*)ws;       ws += 2048;

    // bar (barrier tickets) must be zero at kernel start on EVERY graph
    // replay; the memset is captured in-stream so it re-executes each replay.
    hipMemsetAsync(bar, 0, 2048, stream);

    k_setup<<<512, 256, 0, stream>>>(cb, inite, inputs, cb_bits, est_bits,
                                     in_bits, flags, keys);
    k_packT<<<dim3(32, 16, 4), 256, 0, stream>>>(cb_bits, cbT_bits);
    k_loop<<<NBLK, 256, 0, stream>>>(cb_bits, cbT_bits, est_bits, in_bits,
                                     simf, flags, bar);
    k_argmax<<<dim3(64, 4), 256, 0, stream>>>(cb_bits, est_bits, keys);
    k_final<<<2, 256, 0, stream>>>(keys, flags, out);
}

// Round 9
// 924.476 us; speedup vs baseline: 1.1302x; 1.1302x over previous
//
#include <hip/hip_runtime.h>
#include <stdint.h>

#define B_    128
#define F_    4
#define V_    2048
#define D_    4096
#define DW    64      // D/64 bit-words per (b,f) row
#define VW    32      // V/64 bit-words per d column
#define ITERS 20
#define NKT   16      // K tiles of 128 over V=2048
#define NBLK  512
#define ESLOT (B_ * F_ * DW)        // u64 words per est slot (256 KB)
#define SSLOT ((size_t)F_ * B_ * V_) // f16 elems per simf slot (2 MB)

typedef _Float16 half8 __attribute__((ext_vector_type(8)));
typedef float   floatx4 __attribute__((ext_vector_type(4)));

// ---- coherent (cross-XCD) STORES: relaxed agent atomics (write side only;
// reads are plain cached loads, legal via single-writer buffer rotation).
__device__ __forceinline__ void cstore64(uint64_t* p, uint64_t v) {
    __hip_atomic_store(p, v, __ATOMIC_RELAXED, __HIP_MEMORY_SCOPE_AGENT);
}
__device__ __forceinline__ void cstore32(uint32_t* p, uint32_t v) {
    __hip_atomic_store(p, v, __ATOMIC_RELAXED, __HIP_MEMORY_SCOPE_AGENT);
}

// ---- grid barrier: monotone striped ticket (NO fences, NO resets).
// R7/R8-proven. Bounded spins: failure => wrong answer, never a hang.
__device__ __forceinline__ void xbar(int* bar, int gen) {
    __syncthreads();
    if (threadIdx.x == 0) {
        int s = blockIdx.x & 15;
        int t = __hip_atomic_fetch_add(&bar[s * 16], 1, __ATOMIC_RELAXED,
                                       __HIP_MEMORY_SCOPE_AGENT);
        if (t == gen * (NBLK / 16) - 1)
            __hip_atomic_fetch_add(&bar[256], 1, __ATOMIC_RELAXED,
                                   __HIP_MEMORY_SCOPE_AGENT);
        int spins = 0;
        while (__hip_atomic_load(&bar[256], __ATOMIC_RELAXED,
                                 __HIP_MEMORY_SCOPE_AGENT) < gen * 16) {
            __builtin_amdgcn_s_sleep(2);
            if (++spins > (1 << 16)) break;
        }
    }
    __syncthreads();
}

__device__ __forceinline__ void pack16(const float* __restrict__ x,
                                       uint64_t* __restrict__ bits, int t) {
    const float4* p = (const float4*)x + (size_t)t * 4;
    uint32_t m = 0;
    #pragma unroll
    for (int j = 0; j < 4; ++j) {
        float4 v = p[j];
        m |= (__float_as_uint(v.x) >> 31) << (4 * j + 0);
        m |= (__float_as_uint(v.y) >> 31) << (4 * j + 1);
        m |= (__float_as_uint(v.z) >> 31) << (4 * j + 2);
        m |= (__float_as_uint(v.w) >> 31) << (4 * j + 3);
    }
    ((unsigned short*)bits)[t] = (unsigned short)m;
}

// ------------------------------------------------------------------
// Setup: bit-packs (est -> slot 0) + flag/key zeroing (R6-verified).
// ------------------------------------------------------------------
__global__ __launch_bounds__(256) void k_setup(
        const float* __restrict__ cb, const float* __restrict__ inite,
        const float* __restrict__ inputs,
        uint64_t* __restrict__ cb_bits, uint64_t* __restrict__ est0,
        uint64_t* __restrict__ in_bits,
        int* __restrict__ flags, int* __restrict__ keys) {
    int gtid = blockIdx.x * 256 + threadIdx.x;
    const int T = 512 * 256;
    const int ncb = (F_ * V_ * D_) / 16;
    for (int t = gtid; t < ncb; t += T) pack16(cb, cb_bits, t);
    pack16(inite, est0, gtid);
    if (gtid < (B_ * D_) / 16) pack16(inputs, in_bits, gtid);
    if (gtid < 32) flags[gtid] = 0;
    if (gtid < B_ * F_) keys[gtid] = 0;
}

// ------------------------------------------------------------------
// Transpose cb_bits[f][v][dwords] -> cbT[f][d][vwords] (R6-verified).
// ------------------------------------------------------------------
__global__ void k_packT(const uint64_t* __restrict__ cb_bits,
                        uint64_t* __restrict__ cbT) {
    int vw = blockIdx.x, dwg = blockIdx.y, f = blockIdx.z;
    int lane = threadIdx.x & 63;
    int dw = dwg * 4 + (threadIdx.x >> 6);
    uint64_t w = cb_bits[((size_t)f * V_ + vw * 64 + lane) * DW + dw];
    uint64_t r = 0;
    for (int d2 = 0; d2 < 64; ++d2) {
        uint64_t m = __ballot((unsigned)((w >> d2) & 1));
        if (lane == d2) r = m;
    }
    cbT[((size_t)f * D_ + dw * 64 + lane) * VW + vw] = r;
}

// ------------------------------------------------------------------
// Persistent loop v3 = R7 tiles + BUFFER ROTATION:
//   est[i]  read CACHED by sim/gemm of iter i; est[i+1] written coherent.
//   simf[i] written coherent by sim i; read CACHED by gemm i.
// Each slot is written once, read only after the post-write barrier,
// and its addresses are never cached before the write => plain loads
// are coherent-by-construction. 512 blocks, 48 KB LDS, 2 blocks/CU.
// ------------------------------------------------------------------
__global__ __launch_bounds__(256, 2) void k_loop(
        const uint64_t* __restrict__ cb_bits, const uint64_t* __restrict__ cbT,
        uint64_t* __restrict__ est_base, const uint64_t* __restrict__ in_bits,
        _Float16* __restrict__ simf_base, int* __restrict__ flags, int* bar) {
    const int bid = blockIdx.x;
    const int tid = threadIdx.x;
    int g = 0;

    __shared__ __align__(16) unsigned char LDSU[49152];   // 48 KB, phase-reused
    __shared__ int bd;

    #pragma unroll 1
    for (int i = 0; i < ITERS; ++i) {
        const uint64_t* esti = est_base + (size_t)i * ESLOT;        // read (cached)
        uint64_t*       esto = est_base + (size_t)(i + 1) * ESLOT;  // write (coherent)
        _Float16*       simf = simf_base + (size_t)i * SSLOT;

        // ---- sim: LDS bit-GEMM, tile 64v x 32b (R7 shape) ----
        {
            int vt = bid & 31, bt = (bid >> 5) & 3, f = bid >> 7;
            int v0 = vt * 64, b0 = bt * 32;
            ulonglong2* CB2 = (ulonglong2*)LDSU;            // 64*32 chunks, 32 KB
            ulonglong2* NB2 = (ulonglong2*)(LDSU + 32768);  // 32*32 chunks, 16 KB
            #pragma unroll
            for (int it = 0; it < 8; ++it) {
                int cq = it * 256 + tid;                    // 2048 chunks
                int r = cq >> 5, ch = cq & 31;
                const ulonglong2* src = (const ulonglong2*)(cb_bits + ((size_t)f * V_ + v0 + r) * DW);
                CB2[r * 32 + (ch ^ (r & 7))] = src[ch];     // read-only: cached
            }
            #pragma unroll
            for (int it = 0; it < 4; ++it) {
                int cq = it * 256 + tid;                    // 1024 chunks
                int r = cq >> 5, ch = cq & 31;
                int b = b0 + r;
                const ulonglong2* iv = (const ulonglong2*)(in_bits + (size_t)b * DW);
                const uint64_t* eb = esti + (size_t)b * F_ * DW;
                ulonglong2 i2 = iv[ch];                     // cached
                ulonglong2 e0 = ((const ulonglong2*)(eb + 0 * DW))[ch];  // cached
                ulonglong2 e1 = ((const ulonglong2*)(eb + 1 * DW))[ch];
                ulonglong2 e2 = ((const ulonglong2*)(eb + 2 * DW))[ch];
                ulonglong2 e3 = ((const ulonglong2*)(eb + 3 * DW))[ch];
                uint64_t ex = (f == 0) ? e0.x : (f == 1) ? e1.x : (f == 2) ? e2.x : e3.x;
                uint64_t ey = (f == 0) ? e0.y : (f == 1) ? e1.y : (f == 2) ? e2.y : e3.y;
                ulonglong2 val;
                val.x = i2.x ^ e0.x ^ e1.x ^ e2.x ^ e3.x ^ ex;
                val.y = i2.y ^ e0.y ^ e1.y ^ e2.y ^ e3.y ^ ey;
                NB2[r * 32 + (ch ^ (r & 7))] = val;
            }
            __syncthreads();

            int vv = tid & 15, bb = tid >> 4;
            int svz = vv & 7, sbz = bb & 7;
            int pc[2][4];
            #pragma unroll
            for (int j = 0; j < 2; ++j)
                #pragma unroll
                for (int ii = 0; ii < 4; ++ii) pc[j][ii] = 0;

            #pragma unroll 4
            for (int ch = 0; ch < 32; ++ch) {
                ulonglong2 c[4], n[2];
                #pragma unroll
                for (int ii = 0; ii < 4; ++ii)
                    c[ii] = CB2[(vv + 16 * ii) * 32 + (ch ^ svz)];
                #pragma unroll
                for (int j = 0; j < 2; ++j)
                    n[j] = NB2[(bb + 16 * j) * 32 + (ch ^ sbz)];
                #pragma unroll
                for (int j = 0; j < 2; ++j)
                    #pragma unroll
                    for (int ii = 0; ii < 4; ++ii)
                        pc[j][ii] += __popcll(n[j].x ^ c[ii].x) + __popcll(n[j].y ^ c[ii].y);
            }
            // coherent simf store: pair adjacent lanes (v, v+1) into one u32
            #pragma unroll
            for (int j = 0; j < 2; ++j) {
                int b = b0 + bb + 16 * j;
                #pragma unroll
                for (int ii = 0; ii < 4; ++ii) {
                    int v = v0 + vv + 16 * ii;
                    union { _Float16 hf; unsigned short us; } cv;
                    cv.hf = (_Float16)(2048 - pc[j][ii]);
                    int other = __shfl_xor((int)cv.us, 1, 64);
                    if (!(vv & 1)) {
                        uint32_t packv = (uint32_t)cv.us | ((uint32_t)other << 16);
                        cstore32((uint32_t*)&simf[((size_t)f * B_ + b) * V_ + v], packv);
                    }
                }
            }
        }
        xbar(bar, ++g);

        // ---- gemm: C = sim x (+-1 from cbT); hardsign -> est[i+1] ----
        // R7 shape: 64m x 64n, wave tile 32m x 32n.
        {
            int gnt = bid & 63, gmt = (bid >> 6) & 1, gf = bid >> 7;
            int m0 = gmt * 64, n0 = gnt * 64;
            int lane = tid & 63, wave = tid >> 6;
            int lrow = lane & 15, lq = lane >> 4;
            int wm = wave & 1, wn = wave >> 1;

            uint64_t* Bb = (uint64_t*)LDSU;                 // 16 KB
            _Float16* As = (_Float16*)(LDSU + 16384);       // 16 KB
            if (tid == 0) bd = 0;

            const uint64_t* bsrc = cbT + ((size_t)gf * D_ + n0) * VW;
            #pragma unroll
            for (int p = 0; p < 4; ++p) {
                int chunk = p * 256 + tid;
                int dloc = chunk >> 4, cw = chunk & 15;
                ulonglong2 val = *(const ulonglong2*)&bsrc[dloc * VW + cw * 2];  // cached
                *(ulonglong2*)&Bb[dloc * VW + ((cw ^ (dloc & 15)) * 2)] = val;
            }

            const _Float16* Ab = simf + (size_t)gf * B_ * V_ + (size_t)m0 * V_;
            int arow = tid >> 4, acol = tid & 15;
            half8 areg[4];
            #pragma unroll
            for (int p = 0; p < 4; ++p)
                areg[p] = *(const half8*)&Ab[(size_t)(p * 16 + arow) * V_ + acol * 8];  // cached

            floatx4 acc[2][2] = {};

            const uint64_t SPREAD = 0x1000200040008000ull;
            const uint64_t SMASK  = 0x8000800080008000ull;
            const uint64_t PONE   = 0x3C003C003C003C00ull;

            #pragma unroll 1
            for (int kt = 0; kt < NKT; ++kt) {
                __syncthreads();
                #pragma unroll
                for (int p = 0; p < 4; ++p)
                    *(half8*)&As[(p * 16 + arow) * 128 + ((acol ^ arow) * 8)] = areg[p];
                if (kt + 1 < NKT) {
                    #pragma unroll
                    for (int p = 0; p < 4; ++p)
                        areg[p] = *(const half8*)&Ab[(size_t)(p * 16 + arow) * V_ + (kt + 1) * 128 + acol * 8];
                }
                __syncthreads();

                ulonglong2 bw[2];
                #pragma unroll
                for (int nt2 = 0; nt2 < 2; ++nt2) {
                    int dloc = wn * 32 + nt2 * 16 + lrow;
                    bw[nt2] = *(const ulonglong2*)&Bb[dloc * VW + ((kt ^ (dloc & 15)) * 2)];
                }
                #pragma unroll
                for (int ks = 0; ks < 4; ++ks) {
                    half8 af[2];
                    #pragma unroll
                    for (int mt2 = 0; mt2 < 2; ++mt2) {
                        int row = wm * 32 + mt2 * 16 + lrow;
                        af[mt2] = *(const half8*)&As[row * 128 + (((ks * 4 + lq) ^ lrow) * 8)];
                    }
                    half8 bfrag[2];
                    #pragma unroll
                    for (int nt2 = 0; nt2 < 2; ++nt2) {
                        uint64_t w = (ks < 2) ? bw[nt2].x : bw[nt2].y;
                        uint32_t byte = (uint32_t)(w >> ((((ks & 1) * 4 + lq)) * 8)) & 0xFFu;
                        union { uint64_t q[2]; half8 h; } bu;
                        bu.q[0] = (((uint64_t)(byte & 0xFu) * SPREAD) & SMASK) ^ PONE;
                        bu.q[1] = (((uint64_t)(byte >> 4)   * SPREAD) & SMASK) ^ PONE;
                        bfrag[nt2] = bu.h;
                    }
                    #pragma unroll
                    for (int mt2 = 0; mt2 < 2; ++mt2)
                        #pragma unroll
                        for (int nt2 = 0; nt2 < 2; ++nt2)
                            acc[mt2][nt2] = __builtin_amdgcn_mfma_f32_16x16x32_f16(
                                af[mt2], bfrag[nt2], acc[mt2][nt2], 0, 0, 0);
                }
            }

            // epilogue: hardsign -> LDS bytes -> bit-pack u64 per row
            __syncthreads();
            unsigned char* S = (unsigned char*)As;
            #pragma unroll
            for (int mt2 = 0; mt2 < 2; ++mt2)
                #pragma unroll
                for (int nt2 = 0; nt2 < 2; ++nt2)
                    #pragma unroll
                    for (int r = 0; r < 4; ++r) {
                        int row = wm * 32 + mt2 * 16 + lq * 4 + r;   // C/D: row = quad*4+reg
                        int col = wn * 32 + nt2 * 16 + lrow;         // col = lane&15
                        S[row * 64 + col] = (acc[mt2][nt2][r] < 0.0f) ? 1 : 0;  // sign(0)=+1
                    }
            __syncthreads();
            if (tid < 64) {
                const uint64_t* Sw = (const uint64_t*)S;
                uint64_t m = 0;
                #pragma unroll
                for (int j = 0; j < 8; ++j) {
                    uint64_t w = Sw[tid * 8 + j];
                    m |= ((w * 0x0102040810204080ull) >> 56) << (8 * j);
                }
                size_t widx = ((size_t)(m0 + tid) * F_ + gf) * DW + gnt;
                uint64_t old = esti[widx];                  // cached read of prev slot
                cstore64(&esto[widx], m);                   // coherent write of next slot
                if (old != m) atomicOr(&bd, 1);
            }
            __syncthreads();
            if (tid == 0 && bd) atomicOr(&flags[i], 1);
        }
        if (i + 1 < ITERS) xbar(bar, ++g);
    }
}

// ------------------------------------------------------------------
// argmax (R6-verified), reads final est slot. grid (vt=64, f=4).
// ------------------------------------------------------------------
__global__ __launch_bounds__(256) void k_argmax(
        const uint64_t* __restrict__ cb_bits,
        const uint64_t* __restrict__ est_bits,
        int* __restrict__ keys) {
    int vt = blockIdx.x, f = blockIdx.y;
    int v0 = vt * 32;
    int tid = threadIdx.x;

    __shared__ __align__(16) ulonglong2 EB2[128 * 32];  // 64 KB
    __shared__ __align__(16) ulonglong2 CBa[32 * 32];   // 16 KB

    #pragma unroll
    for (int it = 0; it < 16; ++it) {
        int cq = it * 256 + tid;
        int r = cq >> 5, ch = cq & 31;
        const ulonglong2* src = (const ulonglong2*)(est_bits + ((size_t)r * F_ + f) * DW);
        EB2[r * 32 + (ch ^ (r & 7))] = src[ch];
    }
    #pragma unroll
    for (int it = 0; it < 4; ++it) {
        int cq = it * 256 + tid;
        int r = cq >> 5, ch = cq & 31;
        const ulonglong2* src = (const ulonglong2*)(cb_bits + ((size_t)f * V_ + v0 + r) * DW);
        CBa[r * 32 + (ch ^ (r & 7))] = src[ch];
    }
    __syncthreads();

    int vv = tid & 15, bb = tid >> 4;
    int svz = vv & 7, sbz = bb & 7;
    int pc[8][2];
    #pragma unroll
    for (int j = 0; j < 8; ++j) { pc[j][0] = 0; pc[j][1] = 0; }

    #pragma unroll 4
    for (int ch = 0; ch < 32; ++ch) {
        ulonglong2 c[2], n[8];
        #pragma unroll
        for (int i = 0; i < 2; ++i)
            c[i] = CBa[(vv + 16 * i) * 32 + (ch ^ svz)];
        #pragma unroll
        for (int j = 0; j < 8; ++j)
            n[j] = EB2[(bb + 16 * j) * 32 + (ch ^ sbz)];
        #pragma unroll
        for (int j = 0; j < 8; ++j)
            #pragma unroll
            for (int i = 0; i < 2; ++i)
                pc[j][i] += __popcll(n[j].x ^ c[i].x) + __popcll(n[j].y ^ c[i].y);
    }

    #pragma unroll
    for (int j = 0; j < 8; ++j) {
        int kj = (int)0x80000000;
        #pragma unroll
        for (int i = 0; i < 2; ++i) {
            int v = v0 + vv + 16 * i;
            int m = 2048 - pc[j][i]; if (m < 0) m = -m;
            int key = (m << 11) | (2047 - v);
            if (key > kj) kj = key;
        }
        #pragma unroll
        for (int s = 1; s < 16; s <<= 1) {
            int o = __shfl_xor(kj, s, 64);
            if (o > kj) kj = o;
        }
        if ((tid & 15) == 0)
            atomicMax(&keys[(size_t)(bb + 16 * j) * F_ + f], kj);
    }
}

__global__ void k_final(const int* __restrict__ keys, const int* __restrict__ flags,
                        int* __restrict__ out) {
    int tid = blockIdx.x * blockDim.x + threadIdx.x;
    if (tid < B_ * F_) out[tid] = 2047 - (keys[tid] & 0x7FF);
    if (tid == 0) {
        int k = ITERS - 1;
        for (int i = 0; i < ITERS; ++i) if (flags[i] == 0) { k = i; break; }
        out[B_ * F_] = k;
    }
}

// ------------------------------------------------------------------
extern "C" void kernel_launch(void* const* d_in, const int* in_sizes, int n_in,
                              void* d_out, int out_size, void* d_ws, size_t ws_size,
                              hipStream_t stream) {
    const float* inputs = (const float*)d_in[0];   // (B, D)
    const float* inite  = (const float*)d_in[1];   // (B, F, D)
    const float* cb     = (const float*)d_in[2];   // (F, V, D)
    int* out = (int*)d_out;                        // 512 outcome + 1 k

    char* ws = (char*)d_ws;
    uint64_t* cb_bits  = (uint64_t*)ws;  ws += (size_t)F_ * V_ * DW * 8;        // 4 MiB
    uint64_t* cbT_bits = (uint64_t*)ws;  ws += (size_t)F_ * D_ * VW * 8;        // 4 MiB
    uint64_t* est_base = (uint64_t*)ws;  ws += (size_t)(ITERS + 1) * ESLOT * 8; // 5.25 MiB (21 slots)
    uint64_t* in_bits  = (uint64_t*)ws;  ws += (size_t)B_ * DW * 8;             // 64 KiB
    _Float16* simf     = (_Float16*)ws;  ws += (size_t)ITERS * SSLOT * 2;       // 40 MiB (20 slots)
    int*      flags    = (int*)ws;       ws += 32 * 4;
    int*      keys     = (int*)ws;       ws += B_ * F_ * 4;
    int*      bar      = (int*)ws;       ws += 2048;

    // bar must be zero at kernel start on EVERY graph replay; the memset is
    // captured in-stream so it re-executes each replay.
    hipMemsetAsync(bar, 0, 2048, stream);

    k_setup<<<512, 256, 0, stream>>>(cb, inite, inputs, cb_bits, est_base,
                                     in_bits, flags, keys);
    k_packT<<<dim3(32, 16, 4), 256, 0, stream>>>(cb_bits, cbT_bits);
    k_loop<<<NBLK, 256, 0, stream>>>(cb_bits, cbT_bits, est_base, in_bits,
                                     simf, flags, bar);
    k_argmax<<<dim3(64, 4), 256, 0, stream>>>(cb_bits,
                                              est_base + (size_t)ITERS * ESLOT, keys);
    k_final<<<2, 256, 0, stream>>>(keys, flags, out);
}

// Round 10
// 902.061 us; speedup vs baseline: 1.1583x; 1.0248x over previous
//
#include <hip/hip_runtime.h>
#include <stdint.h>

#define B_    128
#define F_    4
#define V_    2048
#define D_    4096
#define DW    64      // D/64 bit-words per (b,f) row
#define VW    32      // V/64 bit-words per d column
#define ITERS 20
#define NKT   16      // K tiles of 128 over V=2048
#define NBLK  512
#define ESLOT (B_ * F_ * DW)         // u64 words per est slot (256 KB)
#define SSLOT ((size_t)F_ * B_ * V_) // f16 elems per simf slot (2 MB)

typedef _Float16 half8 __attribute__((ext_vector_type(8)));
typedef float   floatx4 __attribute__((ext_vector_type(4)));

// ---- coherent (cross-XCD) STORES: relaxed agent atomics (write side only;
// reads are plain cached loads, legal via single-writer buffer rotation).
__device__ __forceinline__ void cstore64(uint64_t* p, uint64_t v) {
    __hip_atomic_store(p, v, __ATOMIC_RELAXED, __HIP_MEMORY_SCOPE_AGENT);
}
__device__ __forceinline__ void cstore32(uint32_t* p, uint32_t v) {
    __hip_atomic_store(p, v, __ATOMIC_RELAXED, __HIP_MEMORY_SCOPE_AGENT);
}

// ---- grid barrier: monotone striped ticket (NO fences, NO resets).
// R7-R9 proven. Bounded spins: failure => wrong answer, never a hang.
__device__ __forceinline__ void xbar(int* bar, int gen) {
    __syncthreads();
    if (threadIdx.x == 0) {
        int s = blockIdx.x & 15;
        int t = __hip_atomic_fetch_add(&bar[s * 16], 1, __ATOMIC_RELAXED,
                                       __HIP_MEMORY_SCOPE_AGENT);
        if (t == gen * (NBLK / 16) - 1)
            __hip_atomic_fetch_add(&bar[256], 1, __ATOMIC_RELAXED,
                                   __HIP_MEMORY_SCOPE_AGENT);
        int spins = 0;
        while (__hip_atomic_load(&bar[256], __ATOMIC_RELAXED,
                                 __HIP_MEMORY_SCOPE_AGENT) < gen * 16) {
            __builtin_amdgcn_s_sleep(2);
            if (++spins > (1 << 16)) break;
        }
    }
    __syncthreads();
}

__device__ __forceinline__ void pack16(const float* __restrict__ x,
                                       uint64_t* __restrict__ bits, int t) {
    const float4* p = (const float4*)x + (size_t)t * 4;
    uint32_t m = 0;
    #pragma unroll
    for (int j = 0; j < 4; ++j) {
        float4 v = p[j];
        m |= (__float_as_uint(v.x) >> 31) << (4 * j + 0);
        m |= (__float_as_uint(v.y) >> 31) << (4 * j + 1);
        m |= (__float_as_uint(v.z) >> 31) << (4 * j + 2);
        m |= (__float_as_uint(v.w) >> 31) << (4 * j + 3);
    }
    ((unsigned short*)bits)[t] = (unsigned short)m;
}

// ------------------------------------------------------------------
// Setup: bit-packs (est -> slot 0) + flag/key zeroing (R6-verified).
// ------------------------------------------------------------------
__global__ __launch_bounds__(256) void k_setup(
        const float* __restrict__ cb, const float* __restrict__ inite,
        const float* __restrict__ inputs,
        uint64_t* __restrict__ cb_bits, uint64_t* __restrict__ est0,
        uint64_t* __restrict__ in_bits,
        int* __restrict__ flags, int* __restrict__ keys) {
    int gtid = blockIdx.x * 256 + threadIdx.x;
    const int T = 512 * 256;
    const int ncb = (F_ * V_ * D_) / 16;
    for (int t = gtid; t < ncb; t += T) pack16(cb, cb_bits, t);
    pack16(inite, est0, gtid);
    if (gtid < (B_ * D_) / 16) pack16(inputs, in_bits, gtid);
    if (gtid < 32) flags[gtid] = 0;
    if (gtid < B_ * F_) keys[gtid] = 0;
}

// ------------------------------------------------------------------
// Transpose cb_bits[f][v][dwords] -> cbT[f][d][vwords] (R6-verified).
// ------------------------------------------------------------------
__global__ void k_packT(const uint64_t* __restrict__ cb_bits,
                        uint64_t* __restrict__ cbT) {
    int vw = blockIdx.x, dwg = blockIdx.y, f = blockIdx.z;
    int lane = threadIdx.x & 63;
    int dw = dwg * 4 + (threadIdx.x >> 6);
    uint64_t w = cb_bits[((size_t)f * V_ + vw * 64 + lane) * DW + dw];
    uint64_t r = 0;
    for (int d2 = 0; d2 < 64; ++d2) {
        uint64_t m = __ballot((unsigned)((w >> d2) & 1));
        if (lane == d2) r = m;
    }
    cbT[((size_t)f * D_ + dw * 64 + lane) * VW + vw] = r;
}

// ------------------------------------------------------------------
// Persistent loop v4 = R9 (rotation) + XCD-aware remap + once-staged
// constants in 64 KB LDS:
//   CB2 (cb panel, 32K)  staged ONCE   [persistent]
//   Bb  (cbT panel, 16K) staged ONCE   [persistent]
//   NB2 (sim) / As (gemm) share 16K    [per-phase]
// XCD remap (XCD = bid%8, round-robin; speed-only assumption):
//   gemm: bid&7 -> (gmt,gf)  => 64 blocks/XCD share ONE 256KB simf
//         A-panel -> L3 fetch once/XCD, L2 serves the rest.
//   sim:  bid&7 -> (bt,fhi)  => est panel (64KB) shared per XCD.
// Per-XCD working set ~3.3MB < 4MB L2 => everything L2-resident.
// 512 blocks, 64KB+pad LDS x 2 = 132KB < 160KB => 2 blocks/CU
// co-residency preserved (barrier-safe).
// ------------------------------------------------------------------
__global__ __launch_bounds__(256, 2) void k_loop(
        const uint64_t* __restrict__ cb_bits, const uint64_t* __restrict__ cbT,
        uint64_t* __restrict__ est_base, const uint64_t* __restrict__ in_bits,
        _Float16* __restrict__ simf_base, int* __restrict__ flags, int* bar) {
    const int bid = blockIdx.x;
    const int tid = threadIdx.x;
    int g = 0;

    __shared__ __align__(16) unsigned char LDSU[65536];   // 64 KB
    __shared__ int bd;

    // ---- XCD-aware index remaps (bijections over 512 blocks) ----
    const int sgrp = bid & 7;
    const int s_bt = sgrp & 3, s_fhi = sgrp >> 2;
    const int shi  = bid >> 3;                  // 0..63
    const int s_vt = shi & 31, s_flo = shi >> 5;
    const int s_f  = s_fhi + 2 * s_flo;
    const int s_v0 = s_vt * 64, s_b0 = s_bt * 32;

    const int ggrp = bid & 7;
    const int g_mt = ggrp & 1, g_f = ggrp >> 1;
    const int g_nt = bid >> 3;                  // 0..63
    const int g_m0 = g_mt * 64, g_n0 = g_nt * 64;

    ulonglong2* CB2 = (ulonglong2*)LDSU;              // 32 KB persistent
    ulonglong2* NB2 = (ulonglong2*)(LDSU + 32768);    // 16 KB (sim phase)
    _Float16*   As  = (_Float16*)(LDSU + 32768);      // same 16 KB (gemm phase)
    uint64_t*   Bb  = (uint64_t*)(LDSU + 49152);      // 16 KB persistent

    // ---- prologue: stage per-block CONSTANT panels once ----
    #pragma unroll
    for (int it = 0; it < 8; ++it) {
        int cq = it * 256 + tid;                      // 2048 chunks
        int r = cq >> 5, ch = cq & 31;
        const ulonglong2* src = (const ulonglong2*)(cb_bits + ((size_t)s_f * V_ + s_v0 + r) * DW);
        CB2[r * 32 + (ch ^ (r & 7))] = src[ch];
    }
    {
        const uint64_t* bsrc = cbT + ((size_t)g_f * D_ + g_n0) * VW;
        #pragma unroll
        for (int p = 0; p < 4; ++p) {
            int chunk = p * 256 + tid;                // 1024 chunks
            int dloc = chunk >> 4, cw = chunk & 15;
            ulonglong2 val = *(const ulonglong2*)&bsrc[dloc * VW + cw * 2];
            *(ulonglong2*)&Bb[dloc * VW + ((cw ^ (dloc & 15)) * 2)] = val;
        }
    }

    const uint64_t SPREAD = 0x1000200040008000ull;    // bit b -> pos 15+16b
    const uint64_t SMASK  = 0x8000800080008000ull;
    const uint64_t PONE   = 0x3C003C003C003C00ull;    // f16 +1.0 x4

    #pragma unroll 1
    for (int i = 0; i < ITERS; ++i) {
        const uint64_t* esti = est_base + (size_t)i * ESLOT;        // read (cached)
        uint64_t*       esto = est_base + (size_t)(i + 1) * ESLOT;  // write (coherent)
        _Float16*       simf = simf_base + (size_t)i * SSLOT;

        // ---- sim: LDS bit-GEMM, tile 64v x 32b (CB2 already staged) ----
        {
            #pragma unroll
            for (int it = 0; it < 4; ++it) {
                int cq = it * 256 + tid;                    // 1024 chunks
                int r = cq >> 5, ch = cq & 31;
                int b = s_b0 + r;
                const ulonglong2* iv = (const ulonglong2*)(in_bits + (size_t)b * DW);
                const uint64_t* eb = esti + (size_t)b * F_ * DW;
                ulonglong2 i2 = iv[ch];                     // cached
                ulonglong2 e0 = ((const ulonglong2*)(eb + 0 * DW))[ch];  // cached
                ulonglong2 e1 = ((const ulonglong2*)(eb + 1 * DW))[ch];
                ulonglong2 e2 = ((const ulonglong2*)(eb + 2 * DW))[ch];
                ulonglong2 e3 = ((const ulonglong2*)(eb + 3 * DW))[ch];
                uint64_t ex = (s_f == 0) ? e0.x : (s_f == 1) ? e1.x : (s_f == 2) ? e2.x : e3.x;
                uint64_t ey = (s_f == 0) ? e0.y : (s_f == 1) ? e1.y : (s_f == 2) ? e2.y : e3.y;
                ulonglong2 val;
                val.x = i2.x ^ e0.x ^ e1.x ^ e2.x ^ e3.x ^ ex;
                val.y = i2.y ^ e0.y ^ e1.y ^ e2.y ^ e3.y ^ ey;
                NB2[r * 32 + (ch ^ (r & 7))] = val;
            }
            __syncthreads();

            int vv = tid & 15, bb = tid >> 4;
            int svz = vv & 7, sbz = bb & 7;
            int pc[2][4];
            #pragma unroll
            for (int j = 0; j < 2; ++j)
                #pragma unroll
                for (int ii = 0; ii < 4; ++ii) pc[j][ii] = 0;

            #pragma unroll 4
            for (int ch = 0; ch < 32; ++ch) {
                ulonglong2 c[4], n[2];
                #pragma unroll
                for (int ii = 0; ii < 4; ++ii)
                    c[ii] = CB2[(vv + 16 * ii) * 32 + (ch ^ svz)];
                #pragma unroll
                for (int j = 0; j < 2; ++j)
                    n[j] = NB2[(bb + 16 * j) * 32 + (ch ^ sbz)];
                #pragma unroll
                for (int j = 0; j < 2; ++j)
                    #pragma unroll
                    for (int ii = 0; ii < 4; ++ii)
                        pc[j][ii] += __popcll(n[j].x ^ c[ii].x) + __popcll(n[j].y ^ c[ii].y);
            }
            // coherent simf store: pair adjacent lanes (v, v+1) into one u32
            #pragma unroll
            for (int j = 0; j < 2; ++j) {
                int b = s_b0 + bb + 16 * j;
                #pragma unroll
                for (int ii = 0; ii < 4; ++ii) {
                    int v = s_v0 + vv + 16 * ii;
                    union { _Float16 hf; unsigned short us; } cv;
                    cv.hf = (_Float16)(2048 - pc[j][ii]);
                    int other = __shfl_xor((int)cv.us, 1, 64);
                    if (!(vv & 1)) {
                        uint32_t packv = (uint32_t)cv.us | ((uint32_t)other << 16);
                        cstore32((uint32_t*)&simf[((size_t)s_f * B_ + b) * V_ + v], packv);
                    }
                }
            }
        }
        xbar(bar, ++g);

        // ---- gemm: C = sim x (+-1 from Bb); hardsign -> est[i+1] ----
        // 64m x 64n, wave tile 32m x 32n (Bb already staged).
        {
            int lane = tid & 63, wave = tid >> 6;
            int lrow = lane & 15, lq = lane >> 4;
            int wm = wave & 1, wn = wave >> 1;
            if (tid == 0) bd = 0;

            const _Float16* Ab = simf + (size_t)g_f * B_ * V_ + (size_t)g_m0 * V_;
            int arow = tid >> 4, acol = tid & 15;
            half8 areg[4];
            #pragma unroll
            for (int p = 0; p < 4; ++p)
                areg[p] = *(const half8*)&Ab[(size_t)(p * 16 + arow) * V_ + acol * 8];  // cached

            floatx4 acc[2][2] = {};

            #pragma unroll 1
            for (int kt = 0; kt < NKT; ++kt) {
                __syncthreads();
                #pragma unroll
                for (int p = 0; p < 4; ++p)
                    *(half8*)&As[(p * 16 + arow) * 128 + ((acol ^ arow) * 8)] = areg[p];
                if (kt + 1 < NKT) {
                    #pragma unroll
                    for (int p = 0; p < 4; ++p)
                        areg[p] = *(const half8*)&Ab[(size_t)(p * 16 + arow) * V_ + (kt + 1) * 128 + acol * 8];
                }
                __syncthreads();

                ulonglong2 bw[2];
                #pragma unroll
                for (int nt2 = 0; nt2 < 2; ++nt2) {
                    int dloc = wn * 32 + nt2 * 16 + lrow;
                    bw[nt2] = *(const ulonglong2*)&Bb[dloc * VW + ((kt ^ (dloc & 15)) * 2)];
                }
                #pragma unroll
                for (int ks = 0; ks < 4; ++ks) {
                    half8 af[2];
                    #pragma unroll
                    for (int mt2 = 0; mt2 < 2; ++mt2) {
                        int row = wm * 32 + mt2 * 16 + lrow;
                        af[mt2] = *(const half8*)&As[row * 128 + (((ks * 4 + lq) ^ lrow) * 8)];
                    }
                    half8 bfrag[2];
                    #pragma unroll
                    for (int nt2 = 0; nt2 < 2; ++nt2) {
                        uint64_t w = (ks < 2) ? bw[nt2].x : bw[nt2].y;
                        uint32_t byte = (uint32_t)(w >> ((((ks & 1) * 4 + lq)) * 8)) & 0xFFu;
                        union { uint64_t q[2]; half8 h; } bu;
                        bu.q[0] = (((uint64_t)(byte & 0xFu) * SPREAD) & SMASK) ^ PONE;
                        bu.q[1] = (((uint64_t)(byte >> 4)   * SPREAD) & SMASK) ^ PONE;
                        bfrag[nt2] = bu.h;
                    }
                    #pragma unroll
                    for (int mt2 = 0; mt2 < 2; ++mt2)
                        #pragma unroll
                        for (int nt2 = 0; nt2 < 2; ++nt2)
                            acc[mt2][nt2] = __builtin_amdgcn_mfma_f32_16x16x32_f16(
                                af[mt2], bfrag[nt2], acc[mt2][nt2], 0, 0, 0);
                }
            }

            // epilogue: hardsign -> LDS bytes -> bit-pack u64 per row
            __syncthreads();
            unsigned char* S = (unsigned char*)As;
            #pragma unroll
            for (int mt2 = 0; mt2 < 2; ++mt2)
                #pragma unroll
                for (int nt2 = 0; nt2 < 2; ++nt2)
                    #pragma unroll
                    for (int r = 0; r < 4; ++r) {
                        int row = wm * 32 + mt2 * 16 + lq * 4 + r;   // C/D: row = quad*4+reg
                        int col = wn * 32 + nt2 * 16 + lrow;         // col = lane&15
                        S[row * 64 + col] = (acc[mt2][nt2][r] < 0.0f) ? 1 : 0;  // sign(0)=+1
                    }
            __syncthreads();
            if (tid < 64) {
                const uint64_t* Sw = (const uint64_t*)S;
                uint64_t m = 0;
                #pragma unroll
                for (int j = 0; j < 8; ++j) {
                    uint64_t w = Sw[tid * 8 + j];
                    m |= ((w * 0x0102040810204080ull) >> 56) << (8 * j);
                }
                size_t widx = ((size_t)(g_m0 + tid) * F_ + g_f) * DW + g_nt;
                uint64_t old = esti[widx];                  // cached read of prev slot
                cstore64(&esto[widx], m);                   // coherent write of next slot
                if (old != m) atomicOr(&bd, 1);
            }
            __syncthreads();
            if (tid == 0 && bd) atomicOr(&flags[i], 1);
        }
        if (i + 1 < ITERS) xbar(bar, ++g);
    }
}

// ------------------------------------------------------------------
// argmax (R6-verified), reads final est slot. grid (vt=64, f=4).
// ------------------------------------------------------------------
__global__ __launch_bounds__(256) void k_argmax(
        const uint64_t* __restrict__ cb_bits,
        const uint64_t* __restrict__ est_bits,
        int* __restrict__ keys) {
    int vt = blockIdx.x, f = blockIdx.y;
    int v0 = vt * 32;
    int tid = threadIdx.x;

    __shared__ __align__(16) ulonglong2 EB2[128 * 32];  // 64 KB
    __shared__ __align__(16) ulonglong2 CBa[32 * 32];   // 16 KB

    #pragma unroll
    for (int it = 0; it < 16; ++it) {
        int cq = it * 256 + tid;
        int r = cq >> 5, ch = cq & 31;
        const ulonglong2* src = (const ulonglong2*)(est_bits + ((size_t)r * F_ + f) * DW);
        EB2[r * 32 + (ch ^ (r & 7))] = src[ch];
    }
    #pragma unroll
    for (int it = 0; it < 4; ++it) {
        int cq = it * 256 + tid;
        int r = cq >> 5, ch = cq & 31;
        const ulonglong2* src = (const ulonglong2*)(cb_bits + ((size_t)f * V_ + v0 + r) * DW);
        CBa[r * 32 + (ch ^ (r & 7))] = src[ch];
    }
    __syncthreads();

    int vv = tid & 15, bb = tid >> 4;
    int svz = vv & 7, sbz = bb & 7;
    int pc[8][2];
    #pragma unroll
    for (int j = 0; j < 8; ++j) { pc[j][0] = 0; pc[j][1] = 0; }

    #pragma unroll 4
    for (int ch = 0; ch < 32; ++ch) {
        ulonglong2 c[2], n[8];
        #pragma unroll
        for (int i = 0; i < 2; ++i)
            c[i] = CBa[(vv + 16 * i) * 32 + (ch ^ svz)];
        #pragma unroll
        for (int j = 0; j < 8; ++j)
            n[j] = EB2[(bb + 16 * j) * 32 + (ch ^ sbz)];
        #pragma unroll
        for (int j = 0; j < 8; ++j)
            #pragma unroll
            for (int i = 0; i < 2; ++i)
                pc[j][i] += __popcll(n[j].x ^ c[i].x) + __popcll(n[j].y ^ c[i].y);
    }

    #pragma unroll
    for (int j = 0; j < 8; ++j) {
        int kj = (int)0x80000000;
        #pragma unroll
        for (int i = 0; i < 2; ++i) {
            int v = v0 + vv + 16 * i;
            int m = 2048 - pc[j][i]; if (m < 0) m = -m;
            int key = (m << 11) | (2047 - v);
            if (key > kj) kj = key;
        }
        #pragma unroll
        for (int s = 1; s < 16; s <<= 1) {
            int o = __shfl_xor(kj, s, 64);
            if (o > kj) kj = o;
        }
        if ((tid & 15) == 0)
            atomicMax(&keys[(size_t)(bb + 16 * j) * F_ + f], kj);
    }
}

__global__ void k_final(const int* __restrict__ keys, const int* __restrict__ flags,
                        int* __restrict__ out) {
    int tid = blockIdx.x * blockDim.x + threadIdx.x;
    if (tid < B_ * F_) out[tid] = 2047 - (keys[tid] & 0x7FF);
    if (tid == 0) {
        int k = ITERS - 1;
        for (int i = 0; i < ITERS; ++i) if (flags[i] == 0) { k = i; break; }
        out[B_ * F_] = k;
    }
}

// ------------------------------------------------------------------
extern "C" void kernel_launch(void* const* d_in, const int* in_sizes, int n_in,
                              void* d_out, int out_size, void* d_ws, size_t ws_size,
                              hipStream_t stream) {
    const float* inputs = (const float*)d_in[0];   // (B, D)
    const float* inite  = (const float*)d_in[1];   // (B, F, D)
    const float* cb     = (const float*)d_in[2];   // (F, V, D)
    int* out = (int*)d_out;                        // 512 outcome + 1 k

    char* ws = (char*)d_ws;
    uint64_t* cb_bits  = (uint64_t*)ws;  ws += (size_t)F_ * V_ * DW * 8;        // 4 MiB
    uint64_t* cbT_bits = (uint64_t*)ws;  ws += (size_t)F_ * D_ * VW * 8;        // 4 MiB
    uint64_t* est_base = (uint64_t*)ws;  ws += (size_t)(ITERS + 1) * ESLOT * 8; // 5.25 MiB (21 slots)
    uint64_t* in_bits  = (uint64_t*)ws;  ws += (size_t)B_ * DW * 8;             // 64 KiB
    _Float16* simf     = (_Float16*)ws;  ws += (size_t)ITERS * SSLOT * 2;       // 40 MiB (20 slots)
    int*      flags    = (int*)ws;       ws += 32 * 4;
    int*      keys     = (int*)ws;       ws += B_ * F_ * 4;
    int*      bar      = (int*)ws;       ws += 2048;

    // bar must be zero at kernel start on EVERY graph replay; the memset is
    // captured in-stream so it re-executes each replay.
    hipMemsetAsync(bar, 0, 2048, stream);

    k_setup<<<512, 256, 0, stream>>>(cb, inite, inputs, cb_bits, est_base,
                                     in_bits, flags, keys);
    k_packT<<<dim3(32, 16, 4), 256, 0, stream>>>(cb_bits, cbT_bits);
    k_loop<<<NBLK, 256, 0, stream>>>(cb_bits, cbT_bits, est_base, in_bits,
                                     simf, flags, bar);
    k_argmax<<<dim3(64, 4), 256, 0, stream>>>(cb_bits,
                                              est_base + (size_t)ITERS * ESLOT, keys);
    k_final<<<2, 256, 0, stream>>>(keys, flags, out);
}